// Round 6
// baseline (623.879 us; speedup 1.0000x reference)
//
#include <hip/hip_runtime.h>

typedef __attribute__((ext_vector_type(8))) short bf16x8;
typedef __attribute__((ext_vector_type(4))) float f32x4;
typedef unsigned short u16;

#define NBLK 512

__device__ __forceinline__ float bf2f(u16 u) {
    return __builtin_bit_cast(float, ((unsigned int)u) << 16);
}
__device__ __forceinline__ u16 f2bf(float f) {
    unsigned int x = __builtin_bit_cast(unsigned int, f);
    x += 0x7FFFu + ((x >> 16) & 1u);   // RNE
    return (u16)(x >> 16);
}

typedef const __attribute__((address_space(1))) void* gas_t;
typedef __attribute__((address_space(3))) void* las_t;
__device__ __forceinline__ void load_lds16(const u16* g, u16* l) {
    __builtin_amdgcn_global_load_lds((gas_t)g, (las_t)l, 16, 0, 0);
}

// -------- barrier counters live in ws (re-poisoned every call) -> zero them first --------
__global__ void init_bar(int* bar) {
    if (threadIdx.x < 16) bar[threadIdx.x] = 0;
}

// device-scope grid barrier: all NBLK blocks are co-resident by construction
__device__ __forceinline__ void gridbar(int* bar, int idx) {
    __syncthreads();                       // drains this block's global stores (vmcnt before barrier)
    if (threadIdx.x == 0) {
        __threadfence();                   // agent-scope release of prior writes
        __hip_atomic_fetch_add(bar + idx, 1, __ATOMIC_ACQ_REL, __HIP_MEMORY_SCOPE_AGENT);
        while (__hip_atomic_load(bar + idx, __ATOMIC_ACQUIRE, __HIP_MEMORY_SCOPE_AGENT) < NBLK)
            __builtin_amdgcn_s_sleep(8);
    }
    __syncthreads();
    __threadfence();                       // acquire side for all threads
}

// -------- one 64x64 GEMM tile (BK=64, XOR-swizzled LDS), out = A@W^T + bias --------
// EPI: 1 qkv (cols<256 scaled, bf16 out), 2 +f32 residual (f32 out), 3 exact gelu (bf16 out)
template<int N, int K, int EPI>
__device__ void gemm_tile(int bx, int by, const u16* A, const u16* W,
                          const float* bias, const float* res, void* outv, char* smem)
{
    u16* As = (u16*)smem;
    u16* Bs = (u16*)(smem + 8192);
    const int tid  = threadIdx.x;
    const int lane = tid & 63;
    const int wave = tid >> 6;
    const int m0   = bx * 64;
    const int n0   = by * 64;
    const int wm0  = (wave >> 1) * 32;
    const int wn0  = (wave & 1) * 32;

    f32x4 acc[2][2];
    #pragma unroll
    for (int mt = 0; mt < 2; ++mt)
        #pragma unroll
        for (int nt = 0; nt < 2; ++nt)
            acc[mt][nt] = (f32x4){0.f, 0.f, 0.f, 0.f};

    int soff[2];
    #pragma unroll
    for (int r = 0; r < 2; ++r) {
        const int s   = r * 256 + tid;
        const int row = s >> 3;
        const int c   = (s & 7) ^ (row & 7);
        soff[r] = row * K + c * 8;
    }
    const int fr = lane & 15;
    const int fc = lane >> 4;

    for (int k0 = 0; k0 < K; k0 += 64) {
        __syncthreads();
        #pragma unroll
        for (int r = 0; r < 2; ++r) {
            load_lds16(A + (size_t)m0 * K + k0 + soff[r], As + (r * 256 + tid) * 8);
            load_lds16(W + (size_t)n0 * K + k0 + soff[r], Bs + (r * 256 + tid) * 8);
        }
        __syncthreads();
        #pragma unroll
        for (int ks = 0; ks < 2; ++ks) {
            bf16x8 af[2], bw[2];
            #pragma unroll
            for (int mt = 0; mt < 2; ++mt) {
                const int rr   = wm0 + mt * 16 + fr;
                const int phys = (ks * 4 + fc) ^ (rr & 7);
                af[mt] = *(const bf16x8*)(As + rr * 64 + phys * 8);
            }
            #pragma unroll
            for (int nt = 0; nt < 2; ++nt) {
                const int rr   = wn0 + nt * 16 + fr;
                const int phys = (ks * 4 + fc) ^ (rr & 7);
                bw[nt] = *(const bf16x8*)(Bs + rr * 64 + phys * 8);
            }
            #pragma unroll
            for (int mt = 0; mt < 2; ++mt)
                #pragma unroll
                for (int nt = 0; nt < 2; ++nt)
                    acc[mt][nt] = __builtin_amdgcn_mfma_f32_16x16x32_bf16(af[mt], bw[nt], acc[mt][nt], 0, 0, 0);
        }
    }

    const int col = lane & 15;
    const int rb  = (lane >> 4) * 4;
    #pragma unroll
    for (int nt = 0; nt < 2; ++nt) {
        const int n  = n0 + wn0 + nt * 16 + col;
        const float bv = bias[n];
        #pragma unroll
        for (int mt = 0; mt < 2; ++mt) {
            #pragma unroll
            for (int r = 0; r < 4; ++r) {
                const int m = m0 + wm0 + mt * 16 + rb + r;
                float v = acc[mt][nt][r] + bv;
                if (EPI == 1) {
                    if (n < 256) v *= 0.1767766952966369f;  // 1/sqrt(32), q only
                    ((u16*)outv)[(size_t)m * N + n] = f2bf(v);
                }
                if (EPI == 2) {
                    v += res[(size_t)m * N + n];
                    ((float*)outv)[(size_t)m * N + n] = v;
                }
                if (EPI == 3) {
                    v = 0.5f * v * (1.0f + erff(v * 0.7071067811865475f));
                    ((u16*)outv)[(size_t)m * N + n] = f2bf(v);
                }
            }
        }
    }
}

// -------- proj + residual + LN2 fused tile: 64 rows x all 256 cols, BK=32 --------
__device__ void proj_ln_tile(int bx, const u16* A, const u16* W, const float* pb,
                             const float* xres, const float* g2, const float* b2,
                             float* x1, u16* ln2out, char* smem)
{
    u16* As = (u16*)smem;            // 64 x 32   (4 KB)
    u16* Bs = (u16*)(smem + 4096);   // 256 x 32  (16 KB)
    const int tid  = threadIdx.x;
    const int lane = tid & 63;
    const int wave = tid >> 6;
    const int m0   = bx * 64;

    f32x4 acc[16];
    #pragma unroll
    for (int nt = 0; nt < 16; ++nt) acc[nt] = (f32x4){0.f, 0.f, 0.f, 0.f};

    // staging maps (BK=32: 4 chunks/row, swizzle c ^ (row&3))
    const int arow = tid >> 2, acs = tid & 3;
    const int aoff = (m0 + arow) * 256 + (acs ^ (arow & 3)) * 8;
    int boff[4];
    #pragma unroll
    for (int r = 0; r < 4; ++r) {
        const int s   = r * 256 + tid;
        const int row = s >> 2;
        const int c   = (s & 3) ^ (row & 3);
        boff[r] = row * 256 + c * 8;
    }
    const int fr = lane & 15;
    const int fc = lane >> 4;

    for (int k0 = 0; k0 < 256; k0 += 32) {
        __syncthreads();
        load_lds16(A + aoff + k0, As + tid * 8);
        #pragma unroll
        for (int r = 0; r < 4; ++r)
            load_lds16(W + boff[r] + k0, Bs + (r * 256 + tid) * 8);
        __syncthreads();
        const int ra   = wave * 16 + fr;
        const int pa   = fc ^ (ra & 3);
        bf16x8 af = *(const bf16x8*)(As + ra * 32 + pa * 8);
        #pragma unroll
        for (int nt = 0; nt < 16; ++nt) {
            const int rb_  = nt * 16 + fr;
            const int pb_  = fc ^ (rb_ & 3);
            bf16x8 bw = *(const bf16x8*)(Bs + rb_ * 32 + pb_ * 8);
            acc[nt] = __builtin_amdgcn_mfma_f32_16x16x32_bf16(af, bw, acc[nt], 0, 0, 0);
        }
    }

    // epilogue: v = acc + bias + residual; then LN over the 256 cols of each row
    const int col = lane & 15;
    const int g   = lane >> 4;
    float s[4] = {0.f, 0.f, 0.f, 0.f}, sq[4] = {0.f, 0.f, 0.f, 0.f};
    #pragma unroll
    for (int nt = 0; nt < 16; ++nt) {
        const int n = nt * 16 + col;
        const float bv = pb[n];
        #pragma unroll
        for (int r = 0; r < 4; ++r) {
            const int m = m0 + wave * 16 + g * 4 + r;
            float v = acc[nt][r] + bv + xres[(size_t)m * 256 + n];
            acc[nt][r] = v;
            s[r] += v; sq[r] += v * v;
        }
    }
    #pragma unroll
    for (int off = 1; off < 16; off <<= 1) {
        #pragma unroll
        for (int r = 0; r < 4; ++r) {
            s[r]  += __shfl_xor(s[r], off);
            sq[r] += __shfl_xor(sq[r], off);
        }
    }
    float mean[4], rs[4];
    #pragma unroll
    for (int r = 0; r < 4; ++r) {
        mean[r] = s[r] * (1.0f / 256.0f);
        const float var = sq[r] * (1.0f / 256.0f) - mean[r] * mean[r];
        rs[r] = rsqrtf(var + 1e-5f);
    }
    #pragma unroll
    for (int nt = 0; nt < 16; ++nt) {
        const int n = nt * 16 + col;
        const float gam = g2[n], bet = b2[n];
        #pragma unroll
        for (int r = 0; r < 4; ++r) {
            const int m = m0 + wave * 16 + g * 4 + r;
            const float v = acc[nt][r];
            x1[(size_t)m * 256 + n] = v;
            ln2out[(size_t)m * 256 + n] = f2bf((v - mean[r]) * rs[r] * gam + bet);
        }
    }
}

// -------- neighborhood attention tile: 4x4 spatial x 8 heads per block --------
__device__ void attn_tile(int bid, const u16* qkv, const float* rpb, u16* out, char* smem)
{
    u16*   kv    = (u16*)smem;             // 100*64 u16 = 12800 B
    u16*   qs    = (u16*)(smem + 12800);   // 16*32 u16  = 1024 B
    float* probs = (float*)(smem + 13824); // 16*66 f32  = 4224 B

    const int tid  = threadIdx.x;
    const int bb   = bid >> 8;
    const int rem  = bid & 255;
    const int ti0  = (rem >> 4) << 2;
    const int tj0  = (rem & 15) << 2;
    const int oh   = min(max(ti0 - 3, 0), 54);
    const int ow   = min(max(tj0 - 3, 0), 54);
    const int tokbase = bb * 4096;

    int off_kv[4];
    #pragma unroll
    for (int r = 0; r < 4; ++r) {
        const int sslot = r * 256 + tid;
        const int t  = sslot >> 3;
        const int c  = (sslot & 7) ^ (t & 7);
        const int tr = t / 10, tc = t - tr * 10;
        const int tokg = tokbase + (oh + tr) * 64 + (ow + tc);
        off_kv[r] = tokg * 768 + 256 + ((c & 4) << 6) + (c & 3) * 8;
    }
    const int tq   = tid >> 2;
    const int qoff = (tokbase + (ti0 + (tq >> 2)) * 64 + (tj0 + (tq & 3))) * 768
                   + (tid & 3) * 8;

    const int token = tid >> 4;
    const int part  = tid & 15;
    const int li = token >> 2, lj = token & 3;
    const int i  = ti0 + li,   j  = tj0 + lj;
    const int sh = min(max(i - 3, 0), 57);
    const int sw = min(max(j - 3, 0), 57);
    const int rowbase  = (sh - oh) * 10 + (sw - ow);
    const int rb_const = (sh - i + 6) * 13 + (sw - j + 6);
    const size_t outbase = (size_t)(tokbase + i * 64 + j) * 256 + part * 2;

    for (int h = 0; h < 8; ++h) {
        __syncthreads();
        const int hoff = h * 32;
        #pragma unroll
        for (int r = 0; r < 3; ++r)
            load_lds16(qkv + off_kv[r] + hoff, kv + (r * 256 + tid) * 8);
        if (tid < 32)
            load_lds16(qkv + off_kv[3] + hoff, kv + (768 + tid) * 8);
        if (tid < 64)
            load_lds16(qkv + qoff + hoff, qs + tid * 8);
        __syncthreads();

        float qv[32];
        #pragma unroll
        for (int c = 0; c < 4; ++c) {
            bf16x8 v = *(const bf16x8*)(qs + token * 32 + c * 8);
            #pragma unroll
            for (int e = 0; e < 8; ++e) qv[c * 8 + e] = bf2f((u16)v[e]);
        }

        float sc[4];
        #pragma unroll
        for (int sidx = 0; sidx < 4; ++sidx) {
            const int n = part + sidx * 16;
            if (n < 49) {
                const int kh = n / 7, kw = n - (n / 7) * 7;
                const int hidx = rowbase + kh * 10 + kw;
                float acc = rpb[h * 169 + rb_const + kh * 13 + kw];
                #pragma unroll
                for (int c = 0; c < 4; ++c) {
                    const int slot = (hidx << 3) + (c ^ (hidx & 7));
                    bf16x8 kk = *(const bf16x8*)(kv + slot * 8);
                    #pragma unroll
                    for (int e = 0; e < 8; ++e)
                        acc += qv[c * 8 + e] * bf2f((u16)kk[e]);
                }
                sc[sidx] = acc;
            } else {
                sc[sidx] = -1e30f;
            }
        }
        float mx = fmaxf(fmaxf(sc[0], sc[1]), fmaxf(sc[2], sc[3]));
        #pragma unroll
        for (int off = 1; off < 16; off <<= 1) mx = fmaxf(mx, __shfl_xor(mx, off));
        float ex[4], ssum = 0.f;
        #pragma unroll
        for (int sidx = 0; sidx < 4; ++sidx) {
            ex[sidx] = __expf(sc[sidx] - mx);
            ssum += ex[sidx];
        }
        #pragma unroll
        for (int off = 1; off < 16; off <<= 1) ssum += __shfl_xor(ssum, off);
        const float inv = 1.0f / ssum;
        #pragma unroll
        for (int sidx = 0; sidx < 4; ++sidx)
            probs[token * 66 + part + sidx * 16] = ex[sidx] * inv;
        __syncthreads();

        float o0 = 0.f, o1 = 0.f;
        const int vchunk = 4 + (part >> 2);
        const int vsub   = (part & 3) * 2;
        #pragma unroll
        for (int kh = 0; kh < 7; ++kh) {
            #pragma unroll
            for (int kw = 0; kw < 7; ++kw) {
                const int n    = kh * 7 + kw;
                const int hidx = rowbase + kh * 10 + kw;
                const float p  = probs[token * 66 + n];
                const int slot = (hidx << 3) + (vchunk ^ (hidx & 7));
                const unsigned int vv = *(const unsigned int*)(kv + slot * 8 + vsub);
                o0 += p * bf2f((u16)(vv & 0xffffu));
                o1 += p * bf2f((u16)(vv >> 16));
            }
        }
        ushort2 ov;
        ov.x = f2bf(o0); ov.y = f2bf(o1);
        *(ushort2*)(out + outbase + hoff) = ov;
    }
}

// ==================== the persistent mega-kernel ====================
__global__ __launch_bounds__(256, 2) void mega_kernel(
    const float* __restrict__ x,
    const float* __restrict__ n1g, const float* __restrict__ n1b,
    const float* __restrict__ qkv_w, const float* __restrict__ qkv_b,
    const float* __restrict__ rpb,
    const float* __restrict__ proj_w, const float* __restrict__ proj_b,
    const float* __restrict__ n2g, const float* __restrict__ n2b,
    const float* __restrict__ fc1_w, const float* __restrict__ fc1_b,
    const float* __restrict__ fc2_w, const float* __restrict__ fc2_b,
    float* __restrict__ out, char* __restrict__ wsb, int* __restrict__ bar)
{
    __shared__ __align__(16) char smem[20608];
    const int bid = blockIdx.x;
    const int tid = threadIdx.x;

    u16* wbf   = (u16*)wsb;
    u16* qkvW  = wbf;
    u16* projW = wbf + 196608;
    u16* fc1W  = wbf + 262144;
    u16* fc2W  = wbf + 524288;
    u16*   ln1   = (u16*)(wsb + (2u  << 20));
    u16*   qkvB  = (u16*)(wsb + (6u  << 20));
    u16*   attnB = (u16*)(wsb + (20u << 20));
    u16*   ln2   = (u16*)(wsb + (24u << 20));
    u16*   hbuf  = (u16*)(wsb + (28u << 20));
    float* x1    = (float*)(wsb + (44u << 20));

    // ---- stage A: weight f32->bf16 convert + LN1 ----
    {
        #pragma unroll
        for (int r = 0; r < 6; ++r) {
            const int idx = bid * 256 + tid + r * 131072;
            const float* src; int off;
            if      (idx < 196608) { src = qkv_w;  off = idx; }
            else if (idx < 262144) { src = proj_w; off = idx - 196608; }
            else if (idx < 524288) { src = fc1_w;  off = idx - 262144; }
            else                   { src = fc2_w;  off = idx - 524288; }
            wbf[idx] = f2bf(src[off]);
        }
        const int wave = tid >> 6, lane = tid & 63;
        #pragma unroll
        for (int it = 0; it < 4; ++it) {
            const int tok = bid * 16 + it * 4 + wave;
            float4 v = *(const float4*)(x + (size_t)tok * 256 + lane * 4);
            float s  = v.x + v.y + v.z + v.w;
            float sq = v.x*v.x + v.y*v.y + v.z*v.z + v.w*v.w;
            #pragma unroll
            for (int off = 32; off; off >>= 1) {
                s  += __shfl_xor(s, off);
                sq += __shfl_xor(sq, off);
            }
            const float mean = s * (1.0f / 256.0f);
            const float var  = sq * (1.0f / 256.0f) - mean * mean;
            const float rs   = rsqrtf(var + 1e-5f);
            float4 gv = *(const float4*)(n1g + lane * 4);
            float4 bv = *(const float4*)(n1b + lane * 4);
            ushort4 o;
            o.x = f2bf((v.x - mean) * rs * gv.x + bv.x);
            o.y = f2bf((v.y - mean) * rs * gv.y + bv.y);
            o.z = f2bf((v.z - mean) * rs * gv.z + bv.z);
            o.w = f2bf((v.w - mean) * rs * gv.w + bv.w);
            *(ushort4*)(ln1 + (size_t)tok * 256 + lane * 4) = o;
        }
    }
    gridbar(bar, 0);

    // ---- stage B: qkv GEMM (1536 tiles, 3 per block) ----
    for (int t = bid; t < 1536; t += NBLK)
        gemm_tile<768, 256, 1>(t & 127, t >> 7, ln1, qkvW, qkv_b, nullptr, qkvB, smem);
    gridbar(bar, 1);

    // ---- stage C: neighborhood attention (512 tiles, 1 per block) ----
    attn_tile(bid, qkvB, rpb, attnB, smem);
    gridbar(bar, 2);

    // ---- stage D: proj + residual + LN2 (128 tiles) ----
    if (bid < 128)
        proj_ln_tile(bid, attnB, projW, proj_b, x, n2g, n2b, x1, ln2, smem);
    gridbar(bar, 3);

    // ---- stage E: fc1 + gelu (2048 tiles, 4 per block) ----
    for (int t = bid; t < 2048; t += NBLK)
        gemm_tile<1024, 256, 3>(t & 127, t >> 7, ln2, fc1W, fc1_b, nullptr, hbuf, smem);
    gridbar(bar, 4);

    // ---- stage F: fc2 + residual (512 tiles, 1 per block) ----
    gemm_tile<256, 1024, 2>(bid & 127, bid >> 7, hbuf, fc2W, fc2_b, x1, out, smem);
}

extern "C" void kernel_launch(void* const* d_in, const int* in_sizes, int n_in,
                              void* d_out, int out_size, void* d_ws, size_t ws_size,
                              hipStream_t stream)
{
    const float* x      = (const float*)d_in[0];
    const float* n1g    = (const float*)d_in[1];
    const float* n1b    = (const float*)d_in[2];
    const float* qkv_w  = (const float*)d_in[3];
    const float* qkv_b  = (const float*)d_in[4];
    const float* rpb    = (const float*)d_in[5];
    const float* proj_w = (const float*)d_in[6];
    const float* proj_b = (const float*)d_in[7];
    const float* n2g    = (const float*)d_in[8];
    const float* n2b    = (const float*)d_in[9];
    const float* fc1_w  = (const float*)d_in[10];
    const float* fc1_b  = (const float*)d_in[11];
    const float* fc2_w  = (const float*)d_in[12];
    const float* fc2_b  = (const float*)d_in[13];
    float* out = (float*)d_out;

    char* wsb = (char*)d_ws;
    int*  bar = (int*)(wsb + (64u << 20));   // past all buffers (<52 MB used)

    init_bar<<<1, 64, 0, stream>>>(bar);
    mega_kernel<<<NBLK, 256, 0, stream>>>(
        x, n1g, n1b, qkv_w, qkv_b, rpb, proj_w, proj_b,
        n2g, n2b, fc1_w, fc1_b, fc2_w, fc2_b, out, wsb, bar);
}

// Round 7
// 173.909 us; speedup vs baseline: 3.5874x; 3.5874x over previous
//
#include <hip/hip_runtime.h>

typedef __attribute__((ext_vector_type(8))) short bf16x8;
typedef __attribute__((ext_vector_type(4))) float f32x4;
typedef unsigned short u16;

__device__ __forceinline__ float bf2f(u16 u) {
    return __builtin_bit_cast(float, ((unsigned int)u) << 16);
}
__device__ __forceinline__ u16 f2bf(float f) {
    unsigned int x = __builtin_bit_cast(unsigned int, f);
    x += 0x7FFFu + ((x >> 16) & 1u);   // RNE
    return (u16)(x >> 16);
}
__device__ __forceinline__ int swz(int row) { return (row ^ (row >> 2)) & 3; }

typedef const __attribute__((address_space(1))) void* gas_t;
typedef __attribute__((address_space(3))) void* las_t;
__device__ __forceinline__ void load_lds16(const u16* g, u16* l) {
    __builtin_amdgcn_global_load_lds((gas_t)g, (las_t)l, 16, 0, 0);
}

// ---------------- prep: weight f32->bf16 convert + LN1, one kernel (2048 blocks) ----------------
__global__ __launch_bounds__(256) void prep_kernel(
    const float* __restrict__ x, const float* __restrict__ g, const float* __restrict__ b,
    const float* __restrict__ s0, const float* __restrict__ s1,
    const float* __restrict__ s2, const float* __restrict__ s3,
    u16* __restrict__ wbf, u16* __restrict__ y)
{
    const int bid = blockIdx.x, tid = threadIdx.x;
    // cvt part: 786432 elems over 2048 blocks = 384/block
    {
        int idx = bid * 256 + tid;                    // round 0: 0..524287
        #pragma unroll
        for (int r = 0; r < 2; ++r) {
            if (r == 1) {
                if (tid >= 128) break;
                idx = 524288 + bid * 128 + tid;       // round 1: 524288..786431
            }
            const float* src; int off;
            if      (idx < 196608) { src = s0; off = idx; }
            else if (idx < 262144) { src = s1; off = idx - 196608; }
            else if (idx < 524288) { src = s2; off = idx - 262144; }
            else                   { src = s3; off = idx - 524288; }
            wbf[idx] = f2bf(src[off]);
        }
    }
    // LN1 part: 4 tokens/block
    const int tok  = bid * 4 + (tid >> 6);
    const int lane = tid & 63;
    float4 v = *(const float4*)(x + (size_t)tok * 256 + lane * 4);
    float s  = v.x + v.y + v.z + v.w;
    float sq = v.x*v.x + v.y*v.y + v.z*v.z + v.w*v.w;
    #pragma unroll
    for (int off = 32; off; off >>= 1) {
        s  += __shfl_xor(s, off);
        sq += __shfl_xor(sq, off);
    }
    const float mean = s * (1.0f / 256.0f);
    const float var  = sq * (1.0f / 256.0f) - mean * mean;
    const float rs   = rsqrtf(var + 1e-5f);
    float4 gv = *(const float4*)(g + lane * 4);
    float4 bv = *(const float4*)(b + lane * 4);
    ushort4 o;
    o.x = f2bf((v.x - mean) * rs * gv.x + bv.x);
    o.y = f2bf((v.y - mean) * rs * gv.y + bv.y);
    o.z = f2bf((v.z - mean) * rs * gv.z + bv.z);
    o.w = f2bf((v.w - mean) * rs * gv.w + bv.w);
    *(ushort4*)(y + (size_t)tok * 256 + lane * 4) = o;
}

// ---------------- m97-style GEMM: block tile 128 x BN, BK=32, swizzled LDS ----------------
// BN=128: 4 waves 2x2, wave tile 64x64 (4x4 acc) -> 8 LDS reads / 16 MFMA per K-step.
// BN=64 : 4 waves 4x1, wave tile 32x64 (2x4 acc) -> 6 reads / 8 MFMA.
// EPI: 1 qkv (cols<256 scaled, bf16 out), 2 +f32 residual (f32 out), 3 exact gelu (bf16 out)
template<int BN, int N, int K, int EPI>
__global__ __launch_bounds__(256) void gemm_m97(
    const u16* __restrict__ A, const u16* __restrict__ W,
    const float* __restrict__ bias, const float* __restrict__ res,
    void* __restrict__ outv)
{
    constexpr int MT = (BN == 128) ? 4 : 2;
    constexpr int NT = 4;
    __shared__ u16 As[128 * 32];
    __shared__ u16 Bs[BN * 32];
    const int tid  = threadIdx.x;
    const int lane = tid & 63;
    const int wave = tid >> 6;
    const int m0   = blockIdx.x * 128;
    const int n0   = blockIdx.y * BN;
    const int wm0  = (BN == 128) ? (wave >> 1) * 64 : wave * 32;
    const int wn0  = (BN == 128) ? (wave & 1) * 64 : 0;

    f32x4 acc[MT][NT];
    #pragma unroll
    for (int mt = 0; mt < MT; ++mt)
        #pragma unroll
        for (int nt = 0; nt < NT; ++nt)
            acc[mt][nt] = (f32x4){0.f, 0.f, 0.f, 0.f};

    // staging maps: slot s -> row s>>2, phys chunk s&3, logical chunk (s&3)^swz(row)
    int aoff[2], boff[BN / 64];
    #pragma unroll
    for (int r = 0; r < 2; ++r) {
        const int s   = r * 256 + tid;
        const int row = s >> 2;
        aoff[r] = row * K + ((s & 3) ^ swz(row)) * 8;
    }
    #pragma unroll
    for (int r = 0; r < BN / 64; ++r) {
        const int s   = r * 256 + tid;
        const int row = s >> 2;
        boff[r] = row * K + ((s & 3) ^ swz(row)) * 8;
    }
    const int fr = lane & 15;
    const int lc = lane >> 4;

    for (int k0 = 0; k0 < K; k0 += 32) {
        __syncthreads();
        #pragma unroll
        for (int r = 0; r < 2; ++r)
            load_lds16(A + (size_t)m0 * K + k0 + aoff[r], As + (r * 256 + tid) * 8);
        #pragma unroll
        for (int r = 0; r < BN / 64; ++r)
            load_lds16(W + (size_t)n0 * K + k0 + boff[r], Bs + (r * 256 + tid) * 8);
        __syncthreads();
        bf16x8 af[MT], bw[NT];
        #pragma unroll
        for (int mt = 0; mt < MT; ++mt) {
            const int rr = wm0 + mt * 16 + fr;
            af[mt] = *(const bf16x8*)(As + rr * 32 + (lc ^ swz(rr)) * 8);
        }
        #pragma unroll
        for (int nt = 0; nt < NT; ++nt) {
            const int rr = wn0 + nt * 16 + fr;
            bw[nt] = *(const bf16x8*)(Bs + rr * 32 + (lc ^ swz(rr)) * 8);
        }
        #pragma unroll
        for (int mt = 0; mt < MT; ++mt)
            #pragma unroll
            for (int nt = 0; nt < NT; ++nt)
                acc[mt][nt] = __builtin_amdgcn_mfma_f32_16x16x32_bf16(af[mt], bw[nt], acc[mt][nt], 0, 0, 0);
    }

    // C/D layout: col = lane&15, row = (lane>>4)*4 + r
    const int col = lane & 15;
    const int rb  = (lane >> 4) * 4;
    #pragma unroll
    for (int nt = 0; nt < NT; ++nt) {
        const int n  = n0 + wn0 + nt * 16 + col;
        const float bv = bias[n];
        #pragma unroll
        for (int mt = 0; mt < MT; ++mt) {
            #pragma unroll
            for (int r = 0; r < 4; ++r) {
                const int m = m0 + wm0 + mt * 16 + rb + r;
                float v = acc[mt][nt][r] + bv;
                if (EPI == 1) {
                    if (n < 256) v *= 0.1767766952966369f;  // 1/sqrt(32), q only
                    ((u16*)outv)[(size_t)m * N + n] = f2bf(v);
                }
                if (EPI == 2) {
                    v += res[(size_t)m * N + n];
                    ((float*)outv)[(size_t)m * N + n] = v;
                }
                if (EPI == 3) {
                    v = 0.5f * v * (1.0f + erff(v * 0.7071067811865475f));
                    ((u16*)outv)[(size_t)m * N + n] = f2bf(v);
                }
            }
        }
    }
}

// -------- proj + residual + LN2 fused: 64 rows x all 256 cols, BK=32 (128 blocks) --------
__global__ __launch_bounds__(256) void proj_ln_kernel(
    const u16* __restrict__ A, const u16* __restrict__ W, const float* __restrict__ pb,
    const float* __restrict__ xres, const float* __restrict__ g2, const float* __restrict__ b2,
    float* __restrict__ x1, u16* __restrict__ ln2out)
{
    __shared__ u16 As[64 * 32];
    __shared__ u16 Bs[256 * 32];
    const int tid  = threadIdx.x;
    const int lane = tid & 63;
    const int wave = tid >> 6;
    const int m0   = blockIdx.x * 64;

    f32x4 acc[16];
    #pragma unroll
    for (int nt = 0; nt < 16; ++nt) acc[nt] = (f32x4){0.f, 0.f, 0.f, 0.f};

    const int arow = tid >> 2, acs = tid & 3;
    const int aoff = (m0 + arow) * 256 + (acs ^ (arow & 3)) * 8;
    int boff[4];
    #pragma unroll
    for (int r = 0; r < 4; ++r) {
        const int s   = r * 256 + tid;
        const int row = s >> 2;
        boff[r] = row * 256 + ((s & 3) ^ (row & 3)) * 8;
    }
    const int fr = lane & 15;
    const int fc = lane >> 4;

    for (int k0 = 0; k0 < 256; k0 += 32) {
        __syncthreads();
        load_lds16(A + aoff + k0, As + tid * 8);
        #pragma unroll
        for (int r = 0; r < 4; ++r)
            load_lds16(W + boff[r] + k0, Bs + (r * 256 + tid) * 8);
        __syncthreads();
        const int ra = wave * 16 + fr;
        bf16x8 af = *(const bf16x8*)(As + ra * 32 + (fc ^ (ra & 3)) * 8);
        #pragma unroll
        for (int nt = 0; nt < 16; ++nt) {
            const int rbq = nt * 16 + fr;
            bf16x8 bw = *(const bf16x8*)(Bs + rbq * 32 + (fc ^ (rbq & 3)) * 8);
            acc[nt] = __builtin_amdgcn_mfma_f32_16x16x32_bf16(af, bw, acc[nt], 0, 0, 0);
        }
    }

    const int col = lane & 15;
    const int g   = lane >> 4;
    float s[4] = {0.f, 0.f, 0.f, 0.f}, sq[4] = {0.f, 0.f, 0.f, 0.f};
    #pragma unroll
    for (int nt = 0; nt < 16; ++nt) {
        const int n = nt * 16 + col;
        const float bv = pb[n];
        #pragma unroll
        for (int r = 0; r < 4; ++r) {
            const int m = m0 + wave * 16 + g * 4 + r;
            float v = acc[nt][r] + bv + xres[(size_t)m * 256 + n];
            acc[nt][r] = v;
            s[r] += v; sq[r] += v * v;
        }
    }
    #pragma unroll
    for (int off = 1; off < 16; off <<= 1) {
        #pragma unroll
        for (int r = 0; r < 4; ++r) {
            s[r]  += __shfl_xor(s[r], off);
            sq[r] += __shfl_xor(sq[r], off);
        }
    }
    float mean[4], rs[4];
    #pragma unroll
    for (int r = 0; r < 4; ++r) {
        mean[r] = s[r] * (1.0f / 256.0f);
        const float var = sq[r] * (1.0f / 256.0f) - mean[r] * mean[r];
        rs[r] = rsqrtf(var + 1e-5f);
    }
    #pragma unroll
    for (int nt = 0; nt < 16; ++nt) {
        const int n = nt * 16 + col;
        const float gam = g2[n], bet = b2[n];
        #pragma unroll
        for (int r = 0; r < 4; ++r) {
            const int m = m0 + wave * 16 + g * 4 + r;
            const float v = acc[nt][r];
            x1[(size_t)m * 256 + n] = v;
            ln2out[(size_t)m * 256 + n] = f2bf((v - mean[r]) * rs[r] * gam + bet);
        }
    }
}

// ---------------- Neighborhood attention, LDS-staged tile version (512 blocks) ----------------
__global__ __launch_bounds__(256, 2) void attn_tile_kernel(
    const u16* __restrict__ qkv, const float* __restrict__ rpb,
    u16* __restrict__ out)
{
    __shared__ u16   kv[100 * 64];
    __shared__ u16   qs[16 * 32];
    __shared__ float probs[16 * 66];

    const int tid  = threadIdx.x;
    const int bb   = blockIdx.x >> 8;
    const int rem  = blockIdx.x & 255;
    const int ti0  = (rem >> 4) << 2;
    const int tj0  = (rem & 15) << 2;
    const int oh   = min(max(ti0 - 3, 0), 54);
    const int ow   = min(max(tj0 - 3, 0), 54);
    const int tokbase = bb * 4096;

    int off_kv[4];
    #pragma unroll
    for (int r = 0; r < 4; ++r) {
        const int s  = r * 256 + tid;
        const int t  = s >> 3;
        const int c  = (s & 7) ^ (t & 7);
        const int tr = t / 10, tc = t - tr * 10;
        const int tokg = tokbase + (oh + tr) * 64 + (ow + tc);
        off_kv[r] = tokg * 768 + 256 + ((c & 4) << 6) + (c & 3) * 8;
    }
    const int tq   = tid >> 2;
    const int qoff = (tokbase + (ti0 + (tq >> 2)) * 64 + (tj0 + (tq & 3))) * 768
                   + (tid & 3) * 8;

    const int token = tid >> 4;
    const int part  = tid & 15;
    const int li = token >> 2, lj = token & 3;
    const int i  = ti0 + li,   j  = tj0 + lj;
    const int sh = min(max(i - 3, 0), 57);
    const int sw = min(max(j - 3, 0), 57);
    const int rowbase  = (sh - oh) * 10 + (sw - ow);
    const int rb_const = (sh - i + 6) * 13 + (sw - j + 6);
    const size_t outbase = (size_t)(tokbase + i * 64 + j) * 256 + part * 2;

    for (int h = 0; h < 8; ++h) {
        __syncthreads();
        const int hoff = h * 32;
        #pragma unroll
        for (int r = 0; r < 3; ++r)
            load_lds16(qkv + off_kv[r] + hoff, kv + (r * 256 + tid) * 8);
        if (tid < 32)
            load_lds16(qkv + off_kv[3] + hoff, kv + (768 + tid) * 8);
        if (tid < 64)
            load_lds16(qkv + qoff + hoff, qs + tid * 8);
        __syncthreads();

        float qv[32];
        #pragma unroll
        for (int c = 0; c < 4; ++c) {
            bf16x8 v = *(const bf16x8*)(qs + token * 32 + c * 8);
            #pragma unroll
            for (int e = 0; e < 8; ++e) qv[c * 8 + e] = bf2f((u16)v[e]);
        }

        float sc[4];
        #pragma unroll
        for (int sidx = 0; sidx < 4; ++sidx) {
            const int n = part + sidx * 16;
            if (n < 49) {
                const int kh = n / 7, kw = n - (n / 7) * 7;
                const int hidx = rowbase + kh * 10 + kw;
                float acc = rpb[h * 169 + rb_const + kh * 13 + kw];
                #pragma unroll
                for (int c = 0; c < 4; ++c) {
                    const int slot = (hidx << 3) + (c ^ (hidx & 7));
                    bf16x8 kk = *(const bf16x8*)(kv + slot * 8);
                    #pragma unroll
                    for (int e = 0; e < 8; ++e)
                        acc += qv[c * 8 + e] * bf2f((u16)kk[e]);
                }
                sc[sidx] = acc;
            } else {
                sc[sidx] = -1e30f;
            }
        }
        float mx = fmaxf(fmaxf(sc[0], sc[1]), fmaxf(sc[2], sc[3]));
        #pragma unroll
        for (int off = 1; off < 16; off <<= 1) mx = fmaxf(mx, __shfl_xor(mx, off));
        float ex[4], ssum = 0.f;
        #pragma unroll
        for (int sidx = 0; sidx < 4; ++sidx) {
            ex[sidx] = __expf(sc[sidx] - mx);
            ssum += ex[sidx];
        }
        #pragma unroll
        for (int off = 1; off < 16; off <<= 1) ssum += __shfl_xor(ssum, off);
        const float inv = 1.0f / ssum;
        #pragma unroll
        for (int sidx = 0; sidx < 4; ++sidx)
            probs[token * 66 + part + sidx * 16] = ex[sidx] * inv;
        __syncthreads();

        float o0 = 0.f, o1 = 0.f;
        const int vchunk = 4 + (part >> 2);
        const int vsub   = (part & 3) * 2;
        #pragma unroll
        for (int kh = 0; kh < 7; ++kh) {
            #pragma unroll
            for (int kw = 0; kw < 7; ++kw) {
                const int n    = kh * 7 + kw;
                const int hidx = rowbase + kh * 10 + kw;
                const float p  = probs[token * 66 + n];
                const int slot = (hidx << 3) + (vchunk ^ (hidx & 7));
                const unsigned int vv = *(const unsigned int*)(kv + slot * 8 + vsub);
                o0 += p * bf2f((u16)(vv & 0xffffu));
                o1 += p * bf2f((u16)(vv >> 16));
            }
        }
        ushort2 ov;
        ov.x = f2bf(o0); ov.y = f2bf(o1);
        *(ushort2*)(out + outbase + hoff) = ov;
    }
}

extern "C" void kernel_launch(void* const* d_in, const int* in_sizes, int n_in,
                              void* d_out, int out_size, void* d_ws, size_t ws_size,
                              hipStream_t stream)
{
    const float* x      = (const float*)d_in[0];
    const float* n1g    = (const float*)d_in[1];
    const float* n1b    = (const float*)d_in[2];
    const float* qkv_w  = (const float*)d_in[3];
    const float* qkv_b  = (const float*)d_in[4];
    const float* rpb    = (const float*)d_in[5];
    const float* proj_w = (const float*)d_in[6];
    const float* proj_b = (const float*)d_in[7];
    const float* n2g    = (const float*)d_in[8];
    const float* n2b    = (const float*)d_in[9];
    const float* fc1_w  = (const float*)d_in[10];
    const float* fc1_b  = (const float*)d_in[11];
    const float* fc2_w  = (const float*)d_in[12];
    const float* fc2_b  = (const float*)d_in[13];
    float* out = (float*)d_out;

    char* wsb = (char*)d_ws;
    u16*   wbf   = (u16*)wsb;                      // 786432 el bf16 weights
    u16*   qkvW  = wbf;
    u16*   projW = wbf + 196608;
    u16*   fc1W  = wbf + 262144;
    u16*   fc2W  = wbf + 524288;
    u16*   ln1   = (u16*)(wsb + 1572864);          // 4 MB
    u16*   attnB = ln1;                            // reuse after qkv gemm
    u16*   qkvB  = (u16*)(wsb + 5767168);          // 12.6 MB
    u16*   ln2   = qkvB;                           // reuse after attn
    u16*   hbuf  = (u16*)(wsb + 9961472);          // 16.8 MB
    float* x1    = (float*)(wsb + 26738688);       // 8 MB f32

    dim3 blk(256);
    prep_kernel<<<2048, blk, 0, stream>>>(x, n1g, n1b, qkv_w, proj_w, fc1_w, fc2_w, wbf, ln1);
    gemm_m97<128, 768, 256, 1><<<dim3(64, 6), blk, 0, stream>>>(ln1, qkvW, qkv_b, nullptr, qkvB);
    attn_tile_kernel<<<512, blk, 0, stream>>>(qkvB, rpb, attnB);
    proj_ln_kernel<<<128, blk, 0, stream>>>(attnB, projW, proj_b, x, n2g, n2b, x1, ln2);
    gemm_m97<128, 1024, 256, 3><<<dim3(64, 8), blk, 0, stream>>>(ln2, fc1W, fc1_b, nullptr, hbuf);
    gemm_m97<64, 256, 1024, 2><<<dim3(64, 4), blk, 0, stream>>>(hbuf, fc2W, fc2_b, x1, out);
}

// Round 8
// 165.875 us; speedup vs baseline: 3.7611x; 1.0484x over previous
//
#include <hip/hip_runtime.h>

typedef __attribute__((ext_vector_type(8))) short bf16x8;
typedef __attribute__((ext_vector_type(4))) float f32x4;
typedef unsigned short u16;

__device__ __forceinline__ float bf2f(u16 u) {
    return __builtin_bit_cast(float, ((unsigned int)u) << 16);
}
__device__ __forceinline__ u16 f2bf(float f) {
    unsigned int x = __builtin_bit_cast(unsigned int, f);
    x += 0x7FFFu + ((x >> 16) & 1u);   // RNE
    return (u16)(x >> 16);
}

typedef const __attribute__((address_space(1))) void* gas_t;
typedef __attribute__((address_space(3))) void* las_t;
__device__ __forceinline__ void load_lds16(const u16* g, u16* l) {
    __builtin_amdgcn_global_load_lds((gas_t)g, (las_t)l, 16, 0, 0);
}

// ---------------- prep: weight f32->bf16 convert + LN1 (2048 blocks) ----------------
__global__ __launch_bounds__(256) void prep_kernel(
    const float* __restrict__ x, const float* __restrict__ g, const float* __restrict__ b,
    const float* __restrict__ s0, const float* __restrict__ s1,
    const float* __restrict__ s2, const float* __restrict__ s3,
    u16* __restrict__ wbf, u16* __restrict__ y)
{
    const int bid = blockIdx.x, tid = threadIdx.x;
    {
        int idx = bid * 256 + tid;                    // round 0: 0..524287
        #pragma unroll
        for (int r = 0; r < 2; ++r) {
            if (r == 1) {
                if (tid >= 128) break;
                idx = 524288 + bid * 128 + tid;       // round 1: 524288..786431
            }
            const float* src; int off;
            if      (idx < 196608) { src = s0; off = idx; }
            else if (idx < 262144) { src = s1; off = idx - 196608; }
            else if (idx < 524288) { src = s2; off = idx - 262144; }
            else                   { src = s3; off = idx - 524288; }
            wbf[idx] = f2bf(src[off]);
        }
    }
    const int tok  = bid * 4 + (tid >> 6);
    const int lane = tid & 63;
    float4 v = *(const float4*)(x + (size_t)tok * 256 + lane * 4);
    float s  = v.x + v.y + v.z + v.w;
    float sq = v.x*v.x + v.y*v.y + v.z*v.z + v.w*v.w;
    #pragma unroll
    for (int off = 32; off; off >>= 1) {
        s  += __shfl_xor(s, off);
        sq += __shfl_xor(sq, off);
    }
    const float mean = s * (1.0f / 256.0f);
    const float var  = sq * (1.0f / 256.0f) - mean * mean;
    const float rs   = rsqrtf(var + 1e-5f);
    float4 gv = *(const float4*)(g + lane * 4);
    float4 bv = *(const float4*)(b + lane * 4);
    ushort4 o;
    o.x = f2bf((v.x - mean) * rs * gv.x + bv.x);
    o.y = f2bf((v.y - mean) * rs * gv.y + bv.y);
    o.z = f2bf((v.z - mean) * rs * gv.z + bv.z);
    o.w = f2bf((v.w - mean) * rs * gv.w + bv.w);
    *(ushort4*)(y + (size_t)tok * 256 + lane * 4) = o;
}

// ------- GEMM: block 128m x 64n, BK=64, wave tile 32x64 (6 ds_read : 8 MFMA) -------
// LDS 24 KB -> ~5 blocks/CU. XOR-chunk swizzle (c ^ (row&7)) on 64-elem rows.
// EPI: 1 qkv (cols<256 scaled, bf16 out), 2 +f32 residual (f32 out), 3 exact gelu (bf16 out)
template<int N, int K, int EPI>
__global__ __launch_bounds__(256) void gemm128x64(
    const u16* __restrict__ A, const u16* __restrict__ W,
    const float* __restrict__ bias, const float* __restrict__ res,
    void* __restrict__ outv)
{
    __shared__ u16 As[128 * 64];
    __shared__ u16 Bs[64 * 64];
    const int tid  = threadIdx.x;
    const int lane = tid & 63;
    const int wave = tid >> 6;
    const int m0   = blockIdx.x * 128;
    const int n0   = blockIdx.y * 64;
    const int wm0  = wave * 32;

    f32x4 acc[2][4];
    #pragma unroll
    for (int mt = 0; mt < 2; ++mt)
        #pragma unroll
        for (int nt = 0; nt < 4; ++nt)
            acc[mt][nt] = (f32x4){0.f, 0.f, 0.f, 0.f};

    // staging: slot s -> row s>>3, phys chunk s&7, logical chunk (s&7)^(row&7)
    int aoff[4], boff[2];
    #pragma unroll
    for (int r = 0; r < 4; ++r) {
        const int s   = r * 256 + tid;
        const int row = s >> 3;
        aoff[r] = row * K + ((s & 7) ^ (row & 7)) * 8;
    }
    #pragma unroll
    for (int r = 0; r < 2; ++r) {
        const int s   = r * 256 + tid;
        const int row = s >> 3;
        boff[r] = row * K + ((s & 7) ^ (row & 7)) * 8;
    }
    const int fr = lane & 15;
    const int lc = lane >> 4;

    for (int k0 = 0; k0 < K; k0 += 64) {
        __syncthreads();
        #pragma unroll
        for (int r = 0; r < 4; ++r)
            load_lds16(A + (size_t)m0 * K + k0 + aoff[r], As + (r * 256 + tid) * 8);
        #pragma unroll
        for (int r = 0; r < 2; ++r)
            load_lds16(W + (size_t)n0 * K + k0 + boff[r], Bs + (r * 256 + tid) * 8);
        __syncthreads();
        #pragma unroll
        for (int ks = 0; ks < 2; ++ks) {
            bf16x8 af[2], bw[4];
            #pragma unroll
            for (int mt = 0; mt < 2; ++mt) {
                const int rr = wm0 + mt * 16 + fr;
                af[mt] = *(const bf16x8*)(As + rr * 64 + ((ks * 4 + lc) ^ (rr & 7)) * 8);
            }
            #pragma unroll
            for (int nt = 0; nt < 4; ++nt) {
                const int rr = nt * 16 + fr;
                bw[nt] = *(const bf16x8*)(Bs + rr * 64 + ((ks * 4 + lc) ^ (rr & 7)) * 8);
            }
            #pragma unroll
            for (int mt = 0; mt < 2; ++mt)
                #pragma unroll
                for (int nt = 0; nt < 4; ++nt)
                    acc[mt][nt] = __builtin_amdgcn_mfma_f32_16x16x32_bf16(af[mt], bw[nt], acc[mt][nt], 0, 0, 0);
        }
    }

    // C/D layout: col = lane&15, row = (lane>>4)*4 + r
    const int col = lane & 15;
    const int rb  = (lane >> 4) * 4;
    #pragma unroll
    for (int nt = 0; nt < 4; ++nt) {
        const int n  = n0 + nt * 16 + col;
        const float bv = bias[n];
        #pragma unroll
        for (int mt = 0; mt < 2; ++mt) {
            #pragma unroll
            for (int r = 0; r < 4; ++r) {
                const int m = m0 + wm0 + mt * 16 + rb + r;
                float v = acc[mt][nt][r] + bv;
                if (EPI == 1) {
                    if (n < 256) v *= 0.1767766952966369f;  // 1/sqrt(32), q only
                    ((u16*)outv)[(size_t)m * N + n] = f2bf(v);
                }
                if (EPI == 2) {
                    v += res[(size_t)m * N + n];
                    ((float*)outv)[(size_t)m * N + n] = v;
                }
                if (EPI == 3) {
                    v = 0.5f * v * (1.0f + erff(v * 0.7071067811865475f));
                    ((u16*)outv)[(size_t)m * N + n] = f2bf(v);
                }
            }
        }
    }
}

// -------- proj + residual + LN2 fused: 64 rows x all 256 cols, BK=32 (128 blocks) --------
__global__ __launch_bounds__(256) void proj_ln_kernel(
    const u16* __restrict__ A, const u16* __restrict__ W, const float* __restrict__ pb,
    const float* __restrict__ xres, const float* __restrict__ g2, const float* __restrict__ b2,
    float* __restrict__ x1, u16* __restrict__ ln2out)
{
    __shared__ u16 As[64 * 32];
    __shared__ u16 Bs[256 * 32];
    const int tid  = threadIdx.x;
    const int lane = tid & 63;
    const int wave = tid >> 6;
    const int m0   = blockIdx.x * 64;

    f32x4 acc[16];
    #pragma unroll
    for (int nt = 0; nt < 16; ++nt) acc[nt] = (f32x4){0.f, 0.f, 0.f, 0.f};

    const int arow = tid >> 2, acs = tid & 3;
    const int aoff = (m0 + arow) * 256 + (acs ^ (arow & 3)) * 8;
    int boff[4];
    #pragma unroll
    for (int r = 0; r < 4; ++r) {
        const int s   = r * 256 + tid;
        const int row = s >> 2;
        boff[r] = row * 256 + ((s & 3) ^ (row & 3)) * 8;
    }
    const int fr = lane & 15;
    const int fc = lane >> 4;

    for (int k0 = 0; k0 < 256; k0 += 32) {
        __syncthreads();
        load_lds16(A + aoff + k0, As + tid * 8);
        #pragma unroll
        for (int r = 0; r < 4; ++r)
            load_lds16(W + boff[r] + k0, Bs + (r * 256 + tid) * 8);
        __syncthreads();
        const int ra = wave * 16 + fr;
        bf16x8 af = *(const bf16x8*)(As + ra * 32 + (fc ^ (ra & 3)) * 8);
        #pragma unroll
        for (int nt = 0; nt < 16; ++nt) {
            const int rbq = nt * 16 + fr;
            bf16x8 bw = *(const bf16x8*)(Bs + rbq * 32 + (fc ^ (rbq & 3)) * 8);
            acc[nt] = __builtin_amdgcn_mfma_f32_16x16x32_bf16(af, bw, acc[nt], 0, 0, 0);
        }
    }

    const int col = lane & 15;
    const int g   = lane >> 4;
    float s[4] = {0.f, 0.f, 0.f, 0.f}, sq[4] = {0.f, 0.f, 0.f, 0.f};
    #pragma unroll
    for (int nt = 0; nt < 16; ++nt) {
        const int n = nt * 16 + col;
        const float bv = pb[n];
        #pragma unroll
        for (int r = 0; r < 4; ++r) {
            const int m = m0 + wave * 16 + g * 4 + r;
            float v = acc[nt][r] + bv + xres[(size_t)m * 256 + n];
            acc[nt][r] = v;
            s[r] += v; sq[r] += v * v;
        }
    }
    #pragma unroll
    for (int off = 1; off < 16; off <<= 1) {
        #pragma unroll
        for (int r = 0; r < 4; ++r) {
            s[r]  += __shfl_xor(s[r], off);
            sq[r] += __shfl_xor(sq[r], off);
        }
    }
    float mean[4], rs[4];
    #pragma unroll
    for (int r = 0; r < 4; ++r) {
        mean[r] = s[r] * (1.0f / 256.0f);
        const float var = sq[r] * (1.0f / 256.0f) - mean[r] * mean[r];
        rs[r] = rsqrtf(var + 1e-5f);
    }
    #pragma unroll
    for (int nt = 0; nt < 16; ++nt) {
        const int n = nt * 16 + col;
        const float gam = g2[n], bet = b2[n];
        #pragma unroll
        for (int r = 0; r < 4; ++r) {
            const int m = m0 + wave * 16 + g * 4 + r;
            const float v = acc[nt][r];
            x1[(size_t)m * 256 + n] = v;
            ln2out[(size_t)m * 256 + n] = f2bf((v - mean[r]) * rs[r] * gam + bet);
        }
    }
}

// ---------------- Neighborhood attention, LDS-staged tile version (512 blocks) ----------------
__global__ __launch_bounds__(256, 2) void attn_tile_kernel(
    const u16* __restrict__ qkv, const float* __restrict__ rpb,
    u16* __restrict__ out)
{
    __shared__ u16   kv[100 * 64];
    __shared__ u16   qs[16 * 32];
    __shared__ float probs[16 * 66];

    const int tid  = threadIdx.x;
    const int bb   = blockIdx.x >> 8;
    const int rem  = blockIdx.x & 255;
    const int ti0  = (rem >> 4) << 2;
    const int tj0  = (rem & 15) << 2;
    const int oh   = min(max(ti0 - 3, 0), 54);
    const int ow   = min(max(tj0 - 3, 0), 54);
    const int tokbase = bb * 4096;

    int off_kv[4];
    #pragma unroll
    for (int r = 0; r < 4; ++r) {
        const int s  = r * 256 + tid;
        const int t  = s >> 3;
        const int c  = (s & 7) ^ (t & 7);
        const int tr = t / 10, tc = t - tr * 10;
        const int tokg = tokbase + (oh + tr) * 64 + (ow + tc);
        off_kv[r] = tokg * 768 + 256 + ((c & 4) << 6) + (c & 3) * 8;
    }
    const int tq   = tid >> 2;
    const int qoff = (tokbase + (ti0 + (tq >> 2)) * 64 + (tj0 + (tq & 3))) * 768
                   + (tid & 3) * 8;

    const int token = tid >> 4;
    const int part  = tid & 15;
    const int li = token >> 2, lj = token & 3;
    const int i  = ti0 + li,   j  = tj0 + lj;
    const int sh = min(max(i - 3, 0), 57);
    const int sw = min(max(j - 3, 0), 57);
    const int rowbase  = (sh - oh) * 10 + (sw - ow);
    const int rb_const = (sh - i + 6) * 13 + (sw - j + 6);
    const size_t outbase = (size_t)(tokbase + i * 64 + j) * 256 + part * 2;

    for (int h = 0; h < 8; ++h) {
        __syncthreads();
        const int hoff = h * 32;
        #pragma unroll
        for (int r = 0; r < 3; ++r)
            load_lds16(qkv + off_kv[r] + hoff, kv + (r * 256 + tid) * 8);
        if (tid < 32)
            load_lds16(qkv + off_kv[3] + hoff, kv + (768 + tid) * 8);
        if (tid < 64)
            load_lds16(qkv + qoff + hoff, qs + tid * 8);
        __syncthreads();

        float qv[32];
        #pragma unroll
        for (int c = 0; c < 4; ++c) {
            bf16x8 v = *(const bf16x8*)(qs + token * 32 + c * 8);
            #pragma unroll
            for (int e = 0; e < 8; ++e) qv[c * 8 + e] = bf2f((u16)v[e]);
        }

        float sc[4];
        #pragma unroll
        for (int sidx = 0; sidx < 4; ++sidx) {
            const int n = part + sidx * 16;
            if (n < 49) {
                const int kh = n / 7, kw = n - (n / 7) * 7;
                const int hidx = rowbase + kh * 10 + kw;
                float acc = rpb[h * 169 + rb_const + kh * 13 + kw];
                #pragma unroll
                for (int c = 0; c < 4; ++c) {
                    const int slot = (hidx << 3) + (c ^ (hidx & 7));
                    bf16x8 kk = *(const bf16x8*)(kv + slot * 8);
                    #pragma unroll
                    for (int e = 0; e < 8; ++e)
                        acc += qv[c * 8 + e] * bf2f((u16)kk[e]);
                }
                sc[sidx] = acc;
            } else {
                sc[sidx] = -1e30f;
            }
        }
        float mx = fmaxf(fmaxf(sc[0], sc[1]), fmaxf(sc[2], sc[3]));
        #pragma unroll
        for (int off = 1; off < 16; off <<= 1) mx = fmaxf(mx, __shfl_xor(mx, off));
        float ex[4], ssum = 0.f;
        #pragma unroll
        for (int sidx = 0; sidx < 4; ++sidx) {
            ex[sidx] = __expf(sc[sidx] - mx);
            ssum += ex[sidx];
        }
        #pragma unroll
        for (int off = 1; off < 16; off <<= 1) ssum += __shfl_xor(ssum, off);
        const float inv = 1.0f / ssum;
        #pragma unroll
        for (int sidx = 0; sidx < 4; ++sidx)
            probs[token * 66 + part + sidx * 16] = ex[sidx] * inv;
        __syncthreads();

        float o0 = 0.f, o1 = 0.f;
        const int vchunk = 4 + (part >> 2);
        const int vsub   = (part & 3) * 2;
        #pragma unroll
        for (int kh = 0; kh < 7; ++kh) {
            #pragma unroll
            for (int kw = 0; kw < 7; ++kw) {
                const int n    = kh * 7 + kw;
                const int hidx = rowbase + kh * 10 + kw;
                const float p  = probs[token * 66 + n];
                const int slot = (hidx << 3) + (vchunk ^ (hidx & 7));
                const unsigned int vv = *(const unsigned int*)(kv + slot * 8 + vsub);
                o0 += p * bf2f((u16)(vv & 0xffffu));
                o1 += p * bf2f((u16)(vv >> 16));
            }
        }
        ushort2 ov;
        ov.x = f2bf(o0); ov.y = f2bf(o1);
        *(ushort2*)(out + outbase + hoff) = ov;
    }
}

extern "C" void kernel_launch(void* const* d_in, const int* in_sizes, int n_in,
                              void* d_out, int out_size, void* d_ws, size_t ws_size,
                              hipStream_t stream)
{
    const float* x      = (const float*)d_in[0];
    const float* n1g    = (const float*)d_in[1];
    const float* n1b    = (const float*)d_in[2];
    const float* qkv_w  = (const float*)d_in[3];
    const float* qkv_b  = (const float*)d_in[4];
    const float* rpb    = (const float*)d_in[5];
    const float* proj_w = (const float*)d_in[6];
    const float* proj_b = (const float*)d_in[7];
    const float* n2g    = (const float*)d_in[8];
    const float* n2b    = (const float*)d_in[9];
    const float* fc1_w  = (const float*)d_in[10];
    const float* fc1_b  = (const float*)d_in[11];
    const float* fc2_w  = (const float*)d_in[12];
    const float* fc2_b  = (const float*)d_in[13];
    float* out = (float*)d_out;

    char* wsb = (char*)d_ws;
    u16*   wbf   = (u16*)wsb;                      // 786432 el bf16 weights
    u16*   qkvW  = wbf;
    u16*   projW = wbf + 196608;
    u16*   fc1W  = wbf + 262144;
    u16*   fc2W  = wbf + 524288;
    u16*   ln1   = (u16*)(wsb + 1572864);          // 4 MB
    u16*   attnB = ln1;                            // reuse after qkv gemm
    u16*   qkvB  = (u16*)(wsb + 5767168);          // 12.6 MB
    u16*   ln2   = qkvB;                           // reuse after attn
    u16*   hbuf  = (u16*)(wsb + 9961472);          // 16.8 MB
    float* x1    = (float*)(wsb + 26738688);       // 8 MB f32

    dim3 blk(256);
    prep_kernel<<<2048, blk, 0, stream>>>(x, n1g, n1b, qkv_w, proj_w, fc1_w, fc2_w, wbf, ln1);
    gemm128x64<768, 256, 1><<<dim3(64, 12), blk, 0, stream>>>(ln1, qkvW, qkv_b, nullptr, qkvB);
    attn_tile_kernel<<<512, blk, 0, stream>>>(qkvB, rpb, attnB);
    proj_ln_kernel<<<128, blk, 0, stream>>>(attnB, projW, proj_b, x, n2g, n2b, x1, ln2);
    gemm128x64<1024, 256, 3><<<dim3(64, 16), blk, 0, stream>>>(ln2, fc1W, fc1_b, nullptr, hbuf);
    gemm128x64<256, 1024, 2><<<dim3(64, 4), blk, 0, stream>>>(hbuf, fc2W, fc2_b, x1, out);
}